// Round 1
// baseline (1752.074 us; speedup 1.0000x reference)
//
#include <hip/hip_runtime.h>

#define NE 50000
#define NN 10000
#define KH 96
#define WN 6928
#define IN_SZ 156

// ---------------- Kernel 1: h = relu(edge_attr @ W1 + b1) ----------------
__global__ __launch_bounds__(256) void mlp1_kernel(
    const float* __restrict__ edge_attr, const float* __restrict__ W1,
    const float* __restrict__ b1, float* __restrict__ h)
{
  __shared__ float ea[8][KH];
  __shared__ float w1s[KH][KH];
  const int tid = threadIdx.x;
  const int e0 = blockIdx.x * 8;

  for (int idx = tid; idx < KH * KH; idx += 256) w1s[idx / KH][idx % KH] = W1[idx];
  for (int idx = tid; idx < 8 * KH; idx += 256) {
    int e = idx / KH, k = idx % KH;
    ea[e][k] = edge_attr[(size_t)(e0 + e) * KH + k];
  }
  __syncthreads();

  const int e = tid >> 5;           // 0..7
  const int j0 = (tid & 31) * 3;    // 0,3,...,93
  float a0 = b1[j0], a1 = b1[j0 + 1], a2 = b1[j0 + 2];
  #pragma unroll 8
  for (int k = 0; k < KH; ++k) {
    float v = ea[e][k];
    a0 = fmaf(v, w1s[k][j0], a0);
    a1 = fmaf(v, w1s[k][j0 + 1], a1);
    a2 = fmaf(v, w1s[k][j0 + 2], a2);
  }
  size_t base = (size_t)(e0 + e) * KH + j0;
  h[base]     = fmaxf(a0, 0.f);
  h[base + 1] = fmaxf(a1, 0.f);
  h[base + 2] = fmaxf(a2, 0.f);
}

// ---------------- Kernel 2: fused w-GEMM + tensor product + scatter ----------------
// One workgroup = 16 edges. 116 output slots/edge:
//   s in [0,48)   : 0e  scalar, I=58, b=48, w2 base 0,    out pos o
//   s in [48,96)  : 0o  scalar, I=58, b=48, w2 base 4144, out pos 108+o
//   s in [96,106) : 1o  vector, I=68, b=10, w2 base 2784, out pos 48+3o+cc
//   s in [106,116): 1e  vector, I=68, b=10, w2 base 3464, out pos 78+3o+cc
__global__ __launch_bounds__(256) void fused_kernel(
    const float* __restrict__ h, const float* __restrict__ node_attr,
    const int* __restrict__ edge_index, const float* __restrict__ edge_sh,
    const float* __restrict__ W2, const float* __restrict__ b2,
    float* __restrict__ acc, float* __restrict__ cnt)
{
  __shared__ float hsT[KH][16];        // h transposed: hsT[k][e]
  __shared__ float inl[16][IN_SZ];     // gathered node_attr[dst]
  __shared__ float f0e[16][58];
  __shared__ float f0o[16][58];
  __shared__ float f1o[3][16][68];     // component-major
  __shared__ float f1e[3][16][68];
  __shared__ float shs[16][4];
  __shared__ int srcs[16];
  __shared__ int dsts[16];

  const int tid = threadIdx.x;
  const int e0 = blockIdx.x * 16;

  if (tid < 16) {
    srcs[tid] = edge_index[e0 + tid];
    dsts[tid] = edge_index[NE + e0 + tid];
  } else if (tid >= 64 && tid < 128) {
    int t = tid - 64;
    shs[t >> 2][t & 3] = edge_sh[(size_t)(e0 + (t >> 2)) * 4 + (t & 3)];
  }
  __syncthreads();

  for (int idx = tid; idx < 16 * IN_SZ; idx += 256) {
    int e = idx / IN_SZ, f = idx % IN_SZ;
    inl[e][f] = node_attr[(size_t)dsts[e] * IN_SZ + f];
  }
  for (int idx = tid; idx < 16 * KH; idx += 256) {
    int e = idx / KH, k = idx % KH;
    hsT[k][e] = h[(size_t)(e0 + e) * KH + k];
  }
  if (tid < 16) atomicAdd(&cnt[srcs[tid]], 1.0f);
  __syncthreads();

  { // ---- feature construction: 16 threads per edge ----
    const int e = tid >> 4, j = tid & 15;
    const float sh0 = shs[e][0], s1x = shs[e][1], s1y = shs[e][2], s1z = shs[e][3];
    const float inv_s3 = 0.57735026918962576f;   // 1/sqrt(3)
    const float inv_s2 = 0.70710678118654752f;   // 1/sqrt(2)
    for (int t = j; t < 48; t += 16) {
      float v0 = inl[e][t];          // in_0e
      float vo = inl[e][108 + t];    // in_0o
      f0e[e][t]      = v0 * sh0;
      f0o[e][10 + t] = vo * sh0;
      f1o[0][e][t] = v0 * s1x; f1o[1][e][t] = v0 * s1y; f1o[2][e][t] = v0 * s1z;
      f1e[0][e][20 + t] = vo * s1x; f1e[1][e][20 + t] = vo * s1y; f1e[2][e][20 + t] = vo * s1z;
    }
    if (j < 10) {
      const int v = j;
      float ax = inl[e][48 + 3 * v], ay = inl[e][48 + 3 * v + 1], az = inl[e][48 + 3 * v + 2]; // in_1o
      float bx = inl[e][78 + 3 * v], by = inl[e][78 + 3 * v + 1], bz = inl[e][78 + 3 * v + 2]; // in_1e
      f0e[e][48 + v] = (ax * s1x + ay * s1y + az * s1z) * inv_s3;
      f0o[e][v]      = (bx * s1x + by * s1y + bz * s1z) * inv_s3;
      f1o[0][e][48 + v] = ax * sh0; f1o[1][e][48 + v] = ay * sh0; f1o[2][e][48 + v] = az * sh0;
      f1o[0][e][58 + v] = (by * s1z - bz * s1y) * inv_s2;
      f1o[1][e][58 + v] = (bz * s1x - bx * s1z) * inv_s2;
      f1o[2][e][58 + v] = (bx * s1y - by * s1x) * inv_s2;
      f1e[0][e][v] = (ay * s1z - az * s1y) * inv_s2;
      f1e[1][e][v] = (az * s1x - ax * s1z) * inv_s2;
      f1e[2][e][v] = (ax * s1y - ay * s1x) * inv_s2;
      f1e[0][e][10 + v] = bx * sh0; f1e[1][e][10 + v] = by * sh0; f1e[2][e][10 + v] = bz * sh0;
    }
  }
  __syncthreads();

  // ---- phase 2: on-the-fly w columns + fold; thread = (slot, edge-half) ----
  const int eh = tid >> 7;      // 0/1 -> edges 0..7 / 8..15
  const int s  = tid & 127;
  const int ebase = eh * 8;
  if (s >= 116) return;         // no barriers after this point

  if (s < 96) {
    // ---- scalar families (0e / 0o): I=58, b=48 ----
    const bool is0e = (s < 48);
    const int o = is0e ? s : s - 48;
    const int cb = is0e ? o : 4144 + o;
    const float* feat = is0e ? &f0e[0][0] : &f0o[0][0];
    const int outbase = is0e ? o : 108 + o;
    float oacc[8] = {0.f, 0.f, 0.f, 0.f, 0.f, 0.f, 0.f, 0.f};

    for (int i0 = 0; i0 < 58; i0 += 2) {
      float wa0[8] = {0.f, 0.f, 0.f, 0.f, 0.f, 0.f, 0.f, 0.f};
      float wa1[8] = {0.f, 0.f, 0.f, 0.f, 0.f, 0.f, 0.f, 0.f};
      const float* wp = W2 + cb + (size_t)i0 * 48;
      #pragma unroll 8
      for (int k = 0; k < KH; ++k) {
        float w0 = wp[0], w1 = wp[48];
        float he[8];
        *(float4*)&he[0] = *(const float4*)&hsT[k][ebase];
        *(float4*)&he[4] = *(const float4*)&hsT[k][ebase + 4];
        #pragma unroll
        for (int e2 = 0; e2 < 8; ++e2) {
          wa0[e2] = fmaf(he[e2], w0, wa0[e2]);
          wa1[e2] = fmaf(he[e2], w1, wa1[e2]);
        }
        wp += WN;
      }
      float bv0 = b2[cb + i0 * 48], bv1 = b2[cb + (i0 + 1) * 48];
      #pragma unroll
      for (int e2 = 0; e2 < 8; ++e2) {
        float fv0 = feat[(ebase + e2) * 58 + i0];
        float fv1 = feat[(ebase + e2) * 58 + i0 + 1];
        oacc[e2] += (wa0[e2] + bv0) * fv0 + (wa1[e2] + bv1) * fv1;
      }
    }
    const float nrm = 0.13130643285972254f;  // 1/sqrt(58)
    #pragma unroll
    for (int e2 = 0; e2 < 8; ++e2)
      atomicAdd(&acc[(size_t)srcs[ebase + e2] * IN_SZ + outbase], oacc[e2] * nrm);
  } else {
    // ---- vector families (1o / 1e): I=68, b=10 ----
    const bool is1o = (s < 106);
    const int o = is1o ? (s - 96) : (s - 106);
    const int cb = (is1o ? 2784 : 3464) + o;
    const float* feat = is1o ? &f1o[0][0][0] : &f1e[0][0][0];
    const int outbase = (is1o ? 48 : 78) + 3 * o;
    float oacc0[8] = {0.f, 0.f, 0.f, 0.f, 0.f, 0.f, 0.f, 0.f};
    float oacc1[8] = {0.f, 0.f, 0.f, 0.f, 0.f, 0.f, 0.f, 0.f};
    float oacc2[8] = {0.f, 0.f, 0.f, 0.f, 0.f, 0.f, 0.f, 0.f};

    for (int i0 = 0; i0 < 68; i0 += 4) {
      float wa[8][4] = {{0.f}};
      const float* wp = W2 + cb + (size_t)i0 * 10;
      #pragma unroll 4
      for (int k = 0; k < KH; ++k) {
        float w0 = wp[0], w1 = wp[10], w2v = wp[20], w3 = wp[30];
        float he[8];
        *(float4*)&he[0] = *(const float4*)&hsT[k][ebase];
        *(float4*)&he[4] = *(const float4*)&hsT[k][ebase + 4];
        #pragma unroll
        for (int e2 = 0; e2 < 8; ++e2) {
          wa[e2][0] = fmaf(he[e2], w0, wa[e2][0]);
          wa[e2][1] = fmaf(he[e2], w1, wa[e2][1]);
          wa[e2][2] = fmaf(he[e2], w2v, wa[e2][2]);
          wa[e2][3] = fmaf(he[e2], w3, wa[e2][3]);
        }
        wp += WN;
      }
      float bv0 = b2[cb + i0 * 10],       bv1 = b2[cb + (i0 + 1) * 10];
      float bv2 = b2[cb + (i0 + 2) * 10], bv3 = b2[cb + (i0 + 3) * 10];
      #pragma unroll
      for (int e2 = 0; e2 < 8; ++e2) {
        float w0 = wa[e2][0] + bv0, w1 = wa[e2][1] + bv1;
        float w2v = wa[e2][2] + bv2, w3 = wa[e2][3] + bv3;
        const float* fp0 = feat + 0 * 16 * 68 + (ebase + e2) * 68 + i0;
        const float* fp1 = feat + 1 * 16 * 68 + (ebase + e2) * 68 + i0;
        const float* fp2 = feat + 2 * 16 * 68 + (ebase + e2) * 68 + i0;
        oacc0[e2] += w0 * fp0[0] + w1 * fp0[1] + w2v * fp0[2] + w3 * fp0[3];
        oacc1[e2] += w0 * fp1[0] + w1 * fp1[1] + w2v * fp1[2] + w3 * fp1[3];
        oacc2[e2] += w0 * fp2[0] + w1 * fp2[1] + w2v * fp2[2] + w3 * fp2[3];
      }
    }
    const float nrm = 0.12126781251816650f;  // 1/sqrt(68)
    #pragma unroll
    for (int e2 = 0; e2 < 8; ++e2) {
      size_t base = (size_t)srcs[ebase + e2] * IN_SZ + outbase;
      atomicAdd(&acc[base],     oacc0[e2] * nrm);
      atomicAdd(&acc[base + 1], oacc1[e2] * nrm);
      atomicAdd(&acc[base + 2], oacc2[e2] * nrm);
    }
  }
}

// ---------------- Kernel 3: out = acc / max(cnt,1) + node_attr ----------------
__global__ __launch_bounds__(256) void finalize_kernel(
    const float* __restrict__ acc, const float* __restrict__ cnt,
    const float* __restrict__ node_attr, float* __restrict__ out)
{
  int idx = blockIdx.x * 256 + threadIdx.x;
  if (idx < NN * IN_SZ) {
    int n = idx / IN_SZ;
    out[idx] = acc[idx] / fmaxf(cnt[n], 1.f) + node_attr[idx];
  }
}

extern "C" void kernel_launch(void* const* d_in, const int* in_sizes, int n_in,
                              void* d_out, int out_size, void* d_ws, size_t ws_size,
                              hipStream_t stream)
{
  const float* node_attr = (const float*)d_in[0];
  const int*   edge_index = (const int*)d_in[1];
  const float* edge_attr = (const float*)d_in[2];
  const float* edge_sh   = (const float*)d_in[3];
  const float* W1 = (const float*)d_in[4];
  const float* b1 = (const float*)d_in[5];
  const float* W2 = (const float*)d_in[6];
  const float* b2 = (const float*)d_in[7];
  float* out = (float*)d_out;

  float* h   = (float*)d_ws;                    // 50000*96
  float* acc = h + (size_t)NE * KH;             // 10000*156
  float* cnt = acc + (size_t)NN * IN_SZ;        // 10000

  hipMemsetAsync(acc, 0, ((size_t)NN * IN_SZ + NN) * sizeof(float), stream);
  mlp1_kernel<<<NE / 8, 256, 0, stream>>>(edge_attr, W1, b1, h);
  fused_kernel<<<NE / 16, 256, 0, stream>>>(h, node_attr, edge_index, edge_sh,
                                            W2, b2, acc, cnt);
  finalize_kernel<<<(NN * IN_SZ + 255) / 256, 256, 0, stream>>>(acc, cnt, node_attr, out);
}